// Round 3
// baseline (3378.313 us; speedup 1.0000x reference)
//
#include <hip/hip_runtime.h>

#define D 256
#define L_TOT 13294

typedef __attribute__((ext_vector_type(8))) __bf16 bf16x8;
typedef __attribute__((ext_vector_type(4))) float f32x4;
typedef __attribute__((ext_vector_type(2))) float f32x2;

__device__ __forceinline__ float bf2f(unsigned short u) {
    return __uint_as_float(((unsigned int)u) << 16);
}
__device__ __forceinline__ unsigned short f2bf(float f) {
    unsigned int u = __float_as_uint(f);
    u += 0x7FFFu + ((u >> 16) & 1u);   // round-to-nearest-even
    return (unsigned short)(u >> 16);
}
// two bf16 packed in a dword -> f32x2 {lo, hi}
__device__ __forceinline__ f32x2 bfpair(unsigned int d) {
    f32x2 r;
    r.x = __uint_as_float(d << 16);
    r.y = __uint_as_float(d & 0xFFFF0000u);
    return r;
}
__device__ __forceinline__ f32x2 fma2(f32x2 a, float w, f32x2 c) {
    return __builtin_elementwise_fma(a, (f32x2){w, w}, c);   // v_pk_fma_f32
}

// ---------------------------------------------------------------------------
// Dtype probe on level_embed: bf16 data -> ~100% sane exponents; fp32 read as
// halfwords -> ~60%. flag=1 means bf16 inputs.
// ---------------------------------------------------------------------------
__global__ void probe_k(const unsigned short* __restrict__ u, int n, int* __restrict__ flag)
{
    __shared__ int cnt;
    if (threadIdx.x == 0) cnt = 0;
    __syncthreads();
    int c = 0;
    for (int i = threadIdx.x; i < n; i += 256) {
        const int e = (u[i] >> 7) & 0xFF;
        if (e == 0 || (e >= 96 && e <= 150)) ++c;
    }
    atomicAdd(&cnt, c);
    __syncthreads();
    if (threadIdx.x == 0) *flag = (cnt * 10 > n * 9) ? 1 : 0;
}

__global__ __launch_bounds__(256) void convert_k(
    const void* __restrict__ src, unsigned short* __restrict__ dst, int n,
    const int* __restrict__ flag)
{
    const int i = blockIdx.x * 256 + threadIdx.x;
    if (i >= n) return;
    if (*flag) dst[i] = ((const unsigned short*)src)[i];
    else       dst[i] = f2bf(((const float*)src)[i]);
}

// Convert + transpose: src (L,K,N) -> dst (L,N,K) bf16.  Dst-linear (coalesced
// writes); strided reads stay in L2 (weights total ~18 MB fp32). One-time cost.
__global__ __launch_bounds__(256) void convt_k(
    const void* __restrict__ src, unsigned short* __restrict__ dst,
    int K, int N, int L, const int* __restrict__ flag)
{
    const long e = (long)blockIdx.x * 256 + threadIdx.x;
    const long tot = (long)L * K * N;
    if (e >= tot) return;
    const int per = K * N;
    const int li = (int)(e / per);
    const int r  = (int)(e - (long)li * per);
    const int n  = r / K;
    const int k  = r - n * K;
    const long s = (long)li * per + (long)k * N + n;
    dst[e] = (*flag) ? ((const unsigned short*)src)[s]
                     : f2bf(((const float*)src)[s]);
}

// ---------------------------------------------------------------------------
// Flatten (B,D,H,W) src inputs -> state bf16 (tok,D).
// ---------------------------------------------------------------------------
__global__ __launch_bounds__(256) void flatten_k(
    const void* __restrict__ s0, const void* __restrict__ s1,
    const void* __restrict__ s2, const void* __restrict__ s3,
    const int* __restrict__ flag, unsigned short* __restrict__ state)
{
    const long e = (long)blockIdx.x * 256 + threadIdx.x;
    const int d = (int)(e & 255);
    const long tok = e >> 8;
    const int b = (int)(tok / L_TOT);
    const int t = (int)(tok - (long)b * L_TOT);
    const void *sp;
    int hw, idx;
    if (t < 10000)      { sp = s0; hw = 10000; idx = t;          }
    else if (t < 12500) { sp = s1; hw = 2500;  idx = t - 10000;  }
    else if (t < 13125) { sp = s2; hw = 625;   idx = t - 12500;  }
    else                { sp = s3; hw = 169;   idx = t - 13125;  }
    const long a = ((long)b * D + d) * hw + idx;
    state[e] = (*flag) ? ((const unsigned short*)sp)[a]
                       : f2bf(((const float*)sp)[a]);
}

// Per-layer q recompute, fully fused: q = x + pos_input + level_embed (bf16).
__global__ __launch_bounds__(256) void posflat_k(
    const void* __restrict__ p0, const void* __restrict__ p1,
    const void* __restrict__ p2, const void* __restrict__ p3,
    const unsigned short* __restrict__ lev, const int* __restrict__ flag,
    const unsigned short* __restrict__ x, unsigned short* __restrict__ q)
{
    const long e = (long)blockIdx.x * 256 + threadIdx.x;
    const int d = (int)(e & 255);
    const long tok = e >> 8;
    const int b = (int)(tok / L_TOT);
    const int t = (int)(tok - (long)b * L_TOT);
    const void *pp;
    int hw, idx, l;
    if (t < 10000)      { pp = p0; hw = 10000; idx = t;          l = 0; }
    else if (t < 12500) { pp = p1; hw = 2500;  idx = t - 10000;  l = 1; }
    else if (t < 13125) { pp = p2; hw = 625;   idx = t - 12500;  l = 2; }
    else                { pp = p3; hw = 169;   idx = t - 13125;  l = 3; }
    const long a = ((long)b * D + d) * hw + idx;
    const float pv = (*flag) ? bf2f(((const unsigned short*)pp)[a])
                             : ((const float*)pp)[a];
    q[e] = f2bf(pv + bf2f(lev[l * D + d]) + bf2f(x[e]));
}

// ---------------------------------------------------------------------------
// MFMA GEMM, 2-phase double-buffered (T3 minimum pipeline):
//   prologue STAGE(buf0); loop { STAGE(buf^1, next); compute(buf); barrier }.
// __syncthreads() drains vmcnt, so staged loads fly under the 32 MFMAs.
// out[M,N] = A[M,K] @ B[K,N] (+bias) (relu) (+resid), bf16 io, fp32 acc.
// B TRANSPOSED: Bt[N][K] row-major. Tile 128x128, BK=64, 4 waves (2x2).
// LDS XOR-swizzle in 16B groups (G4): read byte = row*128 + (grp^(row&7))*16,
// global source pre-swizzled per lane (rule #21).
// SPLIT: block col0>=256 switches to {Bt2, bias2, out2, ldOut2} (block-uniform)
// so offsets(N=256) + logits(N=128) run as one dispatch sharing the A pass.
// grid = dim3(col_blocks, row_blocks).
// ---------------------------------------------------------------------------
template<bool RELU, bool RESID, bool SPLIT>
__global__ __launch_bounds__(256, 2) void mgemm_k(
    const unsigned short* __restrict__ A, int ldA,
    const unsigned short* __restrict__ Bt, int ldB,
    const unsigned short* __restrict__ bias,
    const unsigned short* resid,          // no restrict: may alias out
    unsigned short* out, int ldOut,
    const unsigned short* __restrict__ Bt2,
    const unsigned short* __restrict__ bias2,
    unsigned short* out2, int ldOut2,
    long M, int K)
{
    __shared__ unsigned short As[2 * 8192];
    __shared__ unsigned short Bs[2 * 8192];
    const int tid = threadIdx.x;
    const int l  = tid & 63;
    const int w  = tid >> 6;
    const int wm = w >> 1, wn = w & 1;
    const long row0 = (long)blockIdx.y * 128;
    const int  col0x = blockIdx.x * 128;

    const unsigned short* BtB  = Bt;
    const unsigned short* biasB = bias;
    unsigned short* outB = out;
    int ldO  = ldOut;
    int col0 = col0x;
    if (SPLIT && col0x >= 256) {
        BtB = Bt2; biasB = bias2; outB = out2; ldO = ldOut2; col0 = col0x - 256;
    }

    f32x4 acc[4][4];
#pragma unroll
    for (int i = 0; i < 4; ++i)
#pragma unroll
        for (int j = 0; j < 4; ++j) acc[i][j] = (f32x4){0.f, 0.f, 0.f, 0.f};

    // staging geometry: round i stages 16B chunk; tile row r = i*32 + (tid>>3)
    const int sr = tid >> 3;
    const int sg = tid & 7;

    auto stage = [&](int buf, int k0) {
#pragma unroll
        for (int i = 0; i < 4; ++i) {
            const int r = i * 32 + sr;
            long arow = row0 + r; if (arow >= M) arow = M - 1;   // clamp tail
            const int ke = k0 + ((sg ^ (r & 7)) << 3);           // pre-swizzled src
            const unsigned short* ga = A   + arow * (long)ldA + ke;
            const unsigned short* gb = BtB + (long)(col0 + r) * ldB + ke;
            __builtin_amdgcn_global_load_lds(
                (const __attribute__((address_space(1))) void*)ga,
                (__attribute__((address_space(3))) void*)(As + buf * 8192 + i * 2048 + w * 512),
                16, 0, 0);
            __builtin_amdgcn_global_load_lds(
                (const __attribute__((address_space(1))) void*)gb,
                (__attribute__((address_space(3))) void*)(Bs + buf * 8192 + i * 2048 + w * 512),
                16, 0, 0);
        }
    };

    auto compute = [&](int buf) {
        const unsigned short* Ab = As + buf * 8192;
        const unsigned short* Bb = Bs + buf * 8192;
#pragma unroll
        for (int ks = 0; ks < 2; ++ks) {
            const int cc  = ks * 4 + (l >> 4);
            const int swz = ((cc ^ (l & 7)) << 4);
            bf16x8 af[4], bfr[4];
#pragma unroll
            for (int mi = 0; mi < 4; ++mi) {
                const int ar = wm * 64 + mi * 16 + (l & 15);
                af[mi] = *(const bf16x8*)((const char*)Ab + ar * 128 + swz);
            }
#pragma unroll
            for (int ni = 0; ni < 4; ++ni) {
                const int br = wn * 64 + ni * 16 + (l & 15);
                bfr[ni] = *(const bf16x8*)((const char*)Bb + br * 128 + swz);
            }
#pragma unroll
            for (int mi = 0; mi < 4; ++mi)
#pragma unroll
                for (int ni = 0; ni < 4; ++ni)
                    acc[mi][ni] = __builtin_amdgcn_mfma_f32_16x16x32_bf16(
                        af[mi], bfr[ni], acc[mi][ni], 0, 0, 0);
        }
    };

    stage(0, 0);
    __syncthreads();                 // buf0 ready
    int cur = 0;
    for (int k0 = 64; k0 < K; k0 += 64) {
        stage(cur ^ 1, k0);          // issue next-tile loads (fly under MFMA)
        compute(cur);
        __syncthreads();             // drains vmcnt: next buf ready, cur reusable
        cur ^= 1;
    }
    compute(cur);

    // epilogue: C/D layout col=lane&15, row=(lane>>4)*4+r  [m89/m91]
#pragma unroll
    for (int ni = 0; ni < 4; ++ni) {
        const int col = col0 + wn * 64 + ni * 16 + (l & 15);
        const float bv = biasB ? bf2f(biasB[col]) : 0.f;
#pragma unroll
        for (int mi = 0; mi < 4; ++mi) {
            const long rbase = row0 + wm * 64 + mi * 16 + (l >> 4) * 4;
#pragma unroll
            for (int r = 0; r < 4; ++r) {
                const long rr = rbase + r;
                if (rr >= M) continue;
                float v = acc[mi][ni][r] + bv;
                if (RELU) v = fmaxf(v, 0.f);
                if (RESID) v += bf2f(resid[rr * (long)ldO + col]);
                outB[rr * (long)ldO + col] = f2bf(v);
            }
        }
    }
}

// ---------------------------------------------------------------------------
// Deformable sampling. One block per token.
// Prep (tid<128, u = h*16+lp): softmax fused via 16-lane __shfl_xor reduce
// (no serial 8-thread phase), offsets/logits read directly from global
// (coalesced), tables written as [lp*8+h][4] BYTE offsets + weights so the
// gather reads them as int4/float4 (2 LDS vector reads per j, conflict-free:
// 8 distinct addrs stride 16B, 8-way broadcast across q).
// Gather: tid = g*64 + h*8 + q; per j-step 4 unconditional uint2 loads
// (one wave-load = one full 512B token row, perfectly coalesced) + packed
// f32x2 fma (v_pk_fma_f32). Cross-wave reduce via LDS.
// ---------------------------------------------------------------------------
__global__ __launch_bounds__(256) void sample_k(
    const unsigned short* __restrict__ off, const unsigned short* __restrict__ aw,
    const unsigned short* __restrict__ val, unsigned short* __restrict__ attn)
{
    __shared__ __align__(16) int   cidx[128][4];   // byte offsets into val rows
    __shared__ __align__(16) float cw[128][4];
    __shared__ __align__(16) float red[3][64][4];
    const long tok = blockIdx.x;
    const int tid = threadIdx.x;
    const int b = (int)(tok / L_TOT);
    const int t = (int)(tok - (long)b * L_TOT);

    if (tid < 128) {
        const int u = tid;                       // u = h*16 + lp
        const int mu = (u & 15) * 8 + (u >> 4);  // [lp*8+h]
        // softmax over the 16 samples of this head (16-lane shfl groups)
        const float logit = bf2f(aw[tok * 128 + u]);
        float m = logit;
#pragma unroll
        for (int mk = 1; mk < 16; mk <<= 1) m = fmaxf(m, __shfl_xor(m, mk));
        const float e = expf(logit - m);
        float s = e;
#pragma unroll
        for (int mk = 1; mk < 16; mk <<= 1) s += __shfl_xor(s, mk);
        const float a = e / s;
        // token geometry
        int st0, W0;
        if (t < 10000)      { st0 = 0;     W0 = 100; }
        else if (t < 12500) { st0 = 10000; W0 = 50;  }
        else if (t < 13125) { st0 = 12500; W0 = 25;  }
        else                { st0 = 13125; W0 = 13;  }
        const int i0 = t - st0;
        const int yy = i0 / W0;
        const int xx = i0 - yy * W0;
        const float gx = (xx + 0.5f) / (float)W0;
        const float gy = (yy + 0.5f) / (float)W0;   // square levels
        // sample level
        const int lv = (u >> 2) & 3;
        const int Wv  = (lv == 0) ? 100 : (lv == 1) ? 50 : (lv == 2) ? 25 : 13;
        const int stl = (lv == 0) ? 0 : (lv == 1) ? 10000 : (lv == 2) ? 12500 : 13125;
        const unsigned int op = *(const unsigned int*)(off + tok * 256 + 2 * u);
        const float ox = bf2f((unsigned short)op);
        const float oy = bf2f((unsigned short)(op >> 16));
        const float px = (gx + ox / (float)Wv) * Wv - 0.5f;
        const float py = (gy + oy / (float)Wv) * Wv - 0.5f;
        const float fx = floorf(px), fy = floorf(py);
        const float wx1 = px - fx, wy1 = py - fy;
        const int x0 = (int)fx, y0 = (int)fy;
#pragma unroll
        for (int c = 0; c < 4; ++c) {
            const int xi = x0 + (c & 1);
            const int yi = y0 + (c >> 1);
            const float wgt = ((c & 1) ? wx1 : 1.f - wx1) * ((c >> 1) ? wy1 : 1.f - wy1);
            const bool ok = (xi >= 0) && (xi < Wv) && (yi >= 0) && (yi < Wv);
            cidx[mu][c] = ok ? ((stl + yi * Wv + xi) << 9) : 0;   // *512 bytes
            cw[mu][c]   = ok ? wgt * a : 0.f;
        }
    }
    __syncthreads();
    const int g = tid >> 6;                 // sample group (= wave)
    const int l = tid & 63;
    const int h = l >> 3;                   // head
    const int q = l & 7;                    // channel quad
    const char* vb = (const char*)val + ((long)b * L_TOT) * 512 + h * 64 + q * 8;
    f32x2 A01 = {0.f, 0.f}, A23 = {0.f, 0.f};
#pragma unroll
    for (int j = 0; j < 4; ++j) {
        const int mu = (j * 4 + g) * 8 + h;
        const int4   ci = *(const int4*)(&cidx[mu][0]);
        const float4 wv = *(const float4*)(&cw[mu][0]);
        const uint2 d0 = *(const uint2*)(vb + ci.x);
        const uint2 d1 = *(const uint2*)(vb + ci.y);
        const uint2 d2 = *(const uint2*)(vb + ci.z);
        const uint2 d3 = *(const uint2*)(vb + ci.w);
        A01 = fma2(bfpair(d0.x), wv.x, A01);  A23 = fma2(bfpair(d0.y), wv.x, A23);
        A01 = fma2(bfpair(d1.x), wv.y, A01);  A23 = fma2(bfpair(d1.y), wv.y, A23);
        A01 = fma2(bfpair(d2.x), wv.z, A01);  A23 = fma2(bfpair(d2.y), wv.z, A23);
        A01 = fma2(bfpair(d3.x), wv.w, A01);  A23 = fma2(bfpair(d3.y), wv.w, A23);
    }
    if (g) {
        red[g - 1][l][0] = A01.x; red[g - 1][l][1] = A01.y;
        red[g - 1][l][2] = A23.x; red[g - 1][l][3] = A23.y;
    }
    __syncthreads();
    if (g == 0) {
        float a0 = A01.x, a1 = A01.y, a2 = A23.x, a3 = A23.y;
#pragma unroll
        for (int p = 0; p < 3; ++p) {
            a0 += red[p][l][0]; a1 += red[p][l][1];
            a2 += red[p][l][2]; a3 += red[p][l][3];
        }
        ushort4 o;
        o.x = f2bf(a0); o.y = f2bf(a1); o.z = f2bf(a2); o.w = f2bf(a3);
        *(ushort4*)(attn + tok * 256 + h * 32 + q * 4) = o;
    }
}

// ---------------------------------------------------------------------------
// LayerNorm over D=256. Block = 4 waves = 4 tokens; lane = 4 channels.
// ---------------------------------------------------------------------------
__global__ __launch_bounds__(256) void ln_k(
    const unsigned short* __restrict__ y,
    const unsigned short* __restrict__ g, const unsigned short* __restrict__ bb,
    unsigned short* __restrict__ out, long nt)
{
    const int wv = threadIdx.x >> 6;
    const int lane = threadIdx.x & 63;
    const long tok = (long)blockIdx.x * 4 + wv;
    if (tok >= nt) return;
    const ushort4 v4 = *(const ushort4*)(y + tok * D + lane * 4);
    const float v0 = bf2f(v4.x), v1 = bf2f(v4.y), v2 = bf2f(v4.z), v3 = bf2f(v4.w);
    float s = v0 + v1 + v2 + v3;
#pragma unroll
    for (int m = 1; m < 64; m <<= 1) s += __shfl_xor(s, m);
    const float mean = s * (1.f / D);
    const float d0 = v0 - mean, d1 = v1 - mean, d2 = v2 - mean, d3 = v3 - mean;
    float q = d0 * d0 + d1 * d1 + d2 * d2 + d3 * d3;
#pragma unroll
    for (int m = 1; m < 64; m <<= 1) q += __shfl_xor(q, m);
    const float rstd = rsqrtf(q * (1.f / D) + 1e-5f);
    const int c0 = lane * 4;
    ushort4 o;
    o.x = f2bf(d0 * rstd * bf2f(g[c0 + 0]) + bf2f(bb[c0 + 0]));
    o.y = f2bf(d1 * rstd * bf2f(g[c0 + 1]) + bf2f(bb[c0 + 1]));
    o.z = f2bf(d2 * rstd * bf2f(g[c0 + 2]) + bf2f(bb[c0 + 2]));
    o.w = f2bf(d3 * rstd * bf2f(g[c0 + 3]) + bf2f(bb[c0 + 3]));
    *(ushort4*)(out + tok * D + lane * 4) = o;
}

// ---------------------------------------------------------------------------
// Finalize: OUTPUT IS FP32. d_out[0, osz-4) = final src (bf16 state -> f32);
// d_out[osz-4, osz) = level_start_index as f32.
// ---------------------------------------------------------------------------
__global__ __launch_bounds__(256) void finalize_k(
    const unsigned short* __restrict__ state, float* __restrict__ out, long osz)
{
    const long e = (long)blockIdx.x * 256 + threadIdx.x;
    const long n0 = osz - 4;
    if (e < n0) out[e] = bf2f(state[e]);
    if (e < 4) {
        const float st[4] = {0.f, 10000.f, 12500.f, 13125.f};
        out[n0 + e] = st[e];
    }
}

extern "C" void kernel_launch(void* const* d_in, const int* in_sizes, int n_in,
                              void* d_out, int out_size, void* d_ws, size_t ws_size,
                              hipStream_t stream)
{
    (void)n_in; (void)ws_size;
    const long osz = (long)out_size;
    const long nt = (osz - 4) / D;                      // total tokens
    const int nlayers = in_sizes[9] / (D * D);          // so_w: (NL, 256, 256)
    const int dff = in_sizes[19] / (nlayers * D);       // f1_w: (NL, 256, DFF)

    char* ws = (char*)d_ws;
    int* flag = (int*)ws;  ws += 256;
    unsigned short* wc = (unsigned short*)ws;           // canonical bf16 weights
    long off[25]; long acc_off = 0;
    for (int i = 8; i <= 24; ++i) { off[i] = acc_off; acc_off += in_sizes[i]; }
    ws += ((acc_off * 2 + 255) / 256) * 256;
    const size_t SZ_BF = (size_t)nt * D * 2;
    unsigned short* state     = (unsigned short*)ws;  ws += SZ_BF;  // running src (bf16)
    unsigned short* val_b     = (unsigned short*)ws;  ws += SZ_BF;  // value / h[:,0:256]
    unsigned short* offy_b    = (unsigned short*)ws;  ws += SZ_BF;  // offsets, y / h[:,256:512]
    unsigned short* posattn_b = (unsigned short*)ws;  ws += SZ_BF;  // q, then attn, then ffn-partial
    unsigned short* aw_b      = (unsigned short*)ws;  ws += (size_t)nt * 128 * 2;
    unsigned short* hbuf = val_b;   // [nt][dff/2] spans val_b..offy_b (contiguous)
    // total unchanged (~131.5 MB @ B=4)

    probe_k<<<1, 256, 0, stream>>>((const unsigned short*)d_in[8], in_sizes[8], flag);

    // vectors/biases: plain convert
    const int vecIdx[11] = {8, 10, 12, 14, 16, 17, 18, 20, 22, 23, 24};
    for (int j = 0; j < 11; ++j) {
        const int i = vecIdx[j];
        convert_k<<<(in_sizes[i] + 255) / 256, 256, 0, stream>>>(
            d_in[i], wc + off[i], in_sizes[i], flag);
    }
    // matrices: convert + transpose to [N][K] for MFMA B-fragments
    const int matIdx[6] = {9, 11, 13, 15, 19, 21};
    const int matK[6]   = {D, D, D, D, D, dff};
    const int matN[6]   = {D, 128, D, D, dff, D};
    for (int j = 0; j < 6; ++j) {
        const int i = matIdx[j];
        convt_k<<<(in_sizes[i] + 255) / 256, 256, 0, stream>>>(
            d_in[i], wc + off[i], matK[j], matN[j], nlayers, flag);
    }

    flatten_k<<<(int)nt, 256, 0, stream>>>(
        d_in[0], d_in[2], d_in[4], d_in[6], flag, state);

    const int MB = (int)((nt + 127) / 128);
    const int LB = (int)((nt + 3) / 4);
    const int dh = dff / 2;                     // 512: FFN split so h fits 2 buffers

    for (int i = 0; i < nlayers; ++i) {
        posflat_k<<<(int)nt, 256, 0, stream>>>(                 // q = x+pos+lev
            d_in[1], d_in[3], d_in[5], d_in[7], wc + off[8], flag, state, posattn_b);
        mgemm_k<false, false, false><<<dim3(2, MB), 256, 0, stream>>>( // value
            state, D, wc + off[13] + (long)i * D * D, D, wc + off[14] + i * D,
            nullptr, val_b, D, nullptr, nullptr, nullptr, 0, nt, D);
        // fused: sampling offsets (cols 0-255) + attn logits (cols 256-383)
        mgemm_k<false, false, true><<<dim3(3, MB), 256, 0, stream>>>(
            posattn_b, D, wc + off[9] + (long)i * D * 256, D, wc + off[10] + i * 256,
            nullptr, offy_b, D,
            wc + off[11] + (long)i * D * 128, wc + off[12] + i * 128, aw_b, 128,
            nt, D);
        sample_k<<<(int)nt, 256, 0, stream>>>(offy_b, aw_b, val_b, posattn_b);
        mgemm_k<false, true, false><<<dim3(2, MB), 256, 0, stream>>>(  // out-proj + resid
            posattn_b, D, wc + off[15] + (long)i * D * D, D, wc + off[16] + i * D,
            state, offy_b, D, nullptr, nullptr, nullptr, 0, nt, D);
        ln_k<<<LB, 256, 0, stream>>>(offy_b, wc + off[17] + i * D, wc + off[18] + i * D,
                                     state, nt);
        // FFN as 2 half-dff passes: partial = x + relu(x@W1a+b1a)@W2a + b2,
        // then partial += relu(x@W1b+b1b)@W2b.  h lives in val_b+offy_b.
        mgemm_k<true, false, false><<<dim3(dh / 128, MB), 256, 0, stream>>>(
            state, D, wc + off[19] + (long)i * D * dff, D, wc + off[20] + i * dff,
            nullptr, hbuf, dh, nullptr, nullptr, nullptr, 0, nt, D);
        mgemm_k<false, true, false><<<dim3(2, MB), 256, 0, stream>>>(
            hbuf, dh, wc + off[21] + (long)i * dff * D, dff, wc + off[22] + i * D,
            state, posattn_b, D, nullptr, nullptr, nullptr, 0, nt, dh);
        mgemm_k<true, false, false><<<dim3(dh / 128, MB), 256, 0, stream>>>(
            state, D, wc + off[19] + (long)i * D * dff + (long)dh * D, D,
            wc + off[20] + i * dff + dh, nullptr, hbuf, dh,
            nullptr, nullptr, nullptr, 0, nt, D);
        mgemm_k<false, true, false><<<dim3(2, MB), 256, 0, stream>>>(
            hbuf, dh, wc + off[21] + (long)i * dff * D + dh, dff, nullptr,
            posattn_b, posattn_b, D, nullptr, nullptr, nullptr, 0, nt, dh);
        ln_k<<<LB, 256, 0, stream>>>(posattn_b, wc + off[23] + i * D, wc + off[24] + i * D,
                                     state, nt);
    }

    finalize_k<<<(int)((osz - 4 + 255) / 256), 256, 0, stream>>>(
        state, (float*)d_out, osz);
}

// Round 4
// 2957.957 us; speedup vs baseline: 1.1421x; 1.1421x over previous
//
#include <hip/hip_runtime.h>

#define D 256
#define L_TOT 13294

typedef __attribute__((ext_vector_type(8))) __bf16 bf16x8;
typedef __attribute__((ext_vector_type(4))) float f32x4;
typedef __attribute__((ext_vector_type(2))) float f32x2;

__device__ __forceinline__ float bf2f(unsigned short u) {
    return __uint_as_float(((unsigned int)u) << 16);
}
__device__ __forceinline__ unsigned short f2bf(float f) {
    unsigned int u = __float_as_uint(f);
    u += 0x7FFFu + ((u >> 16) & 1u);   // round-to-nearest-even
    return (unsigned short)(u >> 16);
}
// two bf16 packed in a dword -> f32x2 {lo, hi}
__device__ __forceinline__ f32x2 bfpair(unsigned int d) {
    f32x2 r;
    r.x = __uint_as_float(d << 16);
    r.y = __uint_as_float(d & 0xFFFF0000u);
    return r;
}
__device__ __forceinline__ f32x2 fma2(f32x2 a, float w, f32x2 c) {
    return __builtin_elementwise_fma(a, (f32x2){w, w}, c);   // v_pk_fma_f32
}

// ---------------------------------------------------------------------------
// Dtype probe on level_embed: bf16 data -> ~100% sane exponents; fp32 read as
// halfwords -> ~60%. flag=1 means bf16 inputs.
// ---------------------------------------------------------------------------
__global__ void probe_k(const unsigned short* __restrict__ u, int n, int* __restrict__ flag)
{
    __shared__ int cnt;
    if (threadIdx.x == 0) cnt = 0;
    __syncthreads();
    int c = 0;
    for (int i = threadIdx.x; i < n; i += 256) {
        const int e = (u[i] >> 7) & 0xFF;
        if (e == 0 || (e >= 96 && e <= 150)) ++c;
    }
    atomicAdd(&cnt, c);
    __syncthreads();
    if (threadIdx.x == 0) *flag = (cnt * 10 > n * 9) ? 1 : 0;
}

__global__ __launch_bounds__(256) void convert_k(
    const void* __restrict__ src, unsigned short* __restrict__ dst, int n,
    const int* __restrict__ flag)
{
    const int i = blockIdx.x * 256 + threadIdx.x;
    if (i >= n) return;
    if (*flag) dst[i] = ((const unsigned short*)src)[i];
    else       dst[i] = f2bf(((const float*)src)[i]);
}

// Convert + transpose: src (L,K,N) -> dst (L,N,K) bf16.  Dst-linear (coalesced
// writes); strided reads stay in L2 (weights total ~18 MB fp32). One-time cost.
__global__ __launch_bounds__(256) void convt_k(
    const void* __restrict__ src, unsigned short* __restrict__ dst,
    int K, int N, int L, const int* __restrict__ flag)
{
    const long e = (long)blockIdx.x * 256 + threadIdx.x;
    const long tot = (long)L * K * N;
    if (e >= tot) return;
    const int per = K * N;
    const int li = (int)(e / per);
    const int r  = (int)(e - (long)li * per);
    const int n  = r / K;
    const int k  = r - n * K;
    const long s = (long)li * per + (long)k * N + n;
    dst[e] = (*flag) ? ((const unsigned short*)src)[s]
                     : f2bf(((const float*)src)[s]);
}

// ---------------------------------------------------------------------------
// Flatten (B,D,H,W) src inputs -> state bf16 (tok,D).
// ---------------------------------------------------------------------------
__global__ __launch_bounds__(256) void flatten_k(
    const void* __restrict__ s0, const void* __restrict__ s1,
    const void* __restrict__ s2, const void* __restrict__ s3,
    const int* __restrict__ flag, unsigned short* __restrict__ state)
{
    const long e = (long)blockIdx.x * 256 + threadIdx.x;
    const int d = (int)(e & 255);
    const long tok = e >> 8;
    const int b = (int)(tok / L_TOT);
    const int t = (int)(tok - (long)b * L_TOT);
    const void *sp;
    int hw, idx;
    if (t < 10000)      { sp = s0; hw = 10000; idx = t;          }
    else if (t < 12500) { sp = s1; hw = 2500;  idx = t - 10000;  }
    else if (t < 13125) { sp = s2; hw = 625;   idx = t - 12500;  }
    else                { sp = s3; hw = 169;   idx = t - 13125;  }
    const long a = ((long)b * D + d) * hw + idx;
    state[e] = (*flag) ? ((const unsigned short*)sp)[a]
                       : f2bf(((const float*)sp)[a]);
}

// Layer-invariant pos precompute: posc = pos_input + level_embed (bf16).
__global__ __launch_bounds__(256) void posconst_k(
    const void* __restrict__ p0, const void* __restrict__ p1,
    const void* __restrict__ p2, const void* __restrict__ p3,
    const unsigned short* __restrict__ lev, const int* __restrict__ flag,
    unsigned short* __restrict__ posc)
{
    const long e = (long)blockIdx.x * 256 + threadIdx.x;
    const int d = (int)(e & 255);
    const long tok = e >> 8;
    const int b = (int)(tok / L_TOT);
    const int t = (int)(tok - (long)b * L_TOT);
    const void *pp;
    int hw, idx, l;
    if (t < 10000)      { pp = p0; hw = 10000; idx = t;          l = 0; }
    else if (t < 12500) { pp = p1; hw = 2500;  idx = t - 10000;  l = 1; }
    else if (t < 13125) { pp = p2; hw = 625;   idx = t - 12500;  l = 2; }
    else                { pp = p3; hw = 169;   idx = t - 13125;  l = 3; }
    const long a = ((long)b * D + d) * hw + idx;
    const float pv = (*flag) ? bf2f(((const unsigned short*)pp)[a])
                             : ((const float*)pp)[a];
    posc[e] = f2bf(pv + bf2f(lev[l * D + d]));
}

// q = x + posc, fully coalesced uint4 (8 bf16/thread).
__global__ __launch_bounds__(256) void addq_k(
    const unsigned short* __restrict__ x, const unsigned short* __restrict__ p,
    unsigned short* __restrict__ q, long n8)
{
    const long e = (long)blockIdx.x * 256 + threadIdx.x;
    if (e >= n8) return;
    const uint4 xv = ((const uint4*)x)[e];
    const uint4 pv = ((const uint4*)p)[e];
    uint4 o;
#define ADDPK(a, b) ({ const f32x2 fa = bfpair(a), fb = bfpair(b); \
        (unsigned int)f2bf(fb.x + fa.x) | ((unsigned int)f2bf(fb.y + fa.y) << 16); })
    o.x = ADDPK(xv.x, pv.x); o.y = ADDPK(xv.y, pv.y);
    o.z = ADDPK(xv.z, pv.z); o.w = ADDPK(xv.w, pv.w);
#undef ADDPK
    ((uint4*)q)[e] = o;
}

// Fallback (tight workspace): per-layer q = x + pos_input + level_embed.
__global__ __launch_bounds__(256) void posflat_k(
    const void* __restrict__ p0, const void* __restrict__ p1,
    const void* __restrict__ p2, const void* __restrict__ p3,
    const unsigned short* __restrict__ lev, const int* __restrict__ flag,
    const unsigned short* __restrict__ x, unsigned short* __restrict__ q)
{
    const long e = (long)blockIdx.x * 256 + threadIdx.x;
    const int d = (int)(e & 255);
    const long tok = e >> 8;
    const int b = (int)(tok / L_TOT);
    const int t = (int)(tok - (long)b * L_TOT);
    const void *pp;
    int hw, idx, l;
    if (t < 10000)      { pp = p0; hw = 10000; idx = t;          l = 0; }
    else if (t < 12500) { pp = p1; hw = 2500;  idx = t - 10000;  l = 1; }
    else if (t < 13125) { pp = p2; hw = 625;   idx = t - 12500;  l = 2; }
    else                { pp = p3; hw = 169;   idx = t - 13125;  l = 3; }
    const long a = ((long)b * D + d) * hw + idx;
    const float pv = (*flag) ? bf2f(((const unsigned short*)pp)[a])
                             : ((const float*)pp)[a];
    q[e] = f2bf(pv + bf2f(lev[l * D + d]) + bf2f(x[e]));
}

// ---------------------------------------------------------------------------
// MFMA GEMM, single-buffered m97 structure (stage; sync; compute; sync).
// Round-3 post-mortem: double-buffer (64KB LDS) dropped occupancy 3->2
// blocks/CU and REGRESSED ~20% (m132 failure mode) -- for these short-K,
// latency-bound GEMMs cross-block TLP beats in-block pipelining.
// out[M,N] = A[M,K] @ B[K,N] (+bias) (relu) (+resid), bf16 io, fp32 acc.
// B TRANSPOSED: Bt[N][K] row-major. Tile 128x128, BK=64, 4 waves (2x2).
// LDS XOR-swizzle in 16B groups (G4): read byte = row*128 + (grp^(row&7))*16,
// global source pre-swizzled per lane (rule #21).
// SPLIT: block col0>=256 switches to {Bt2, bias2, out2, ldOut2} (block-uniform)
// so offsets(N=256) + logits(N=128) run as one dispatch sharing the A pass.
// grid = dim3(col_blocks, row_blocks).
// ---------------------------------------------------------------------------
template<bool RELU, bool RESID, bool SPLIT>
__global__ __launch_bounds__(256, 3) void mgemm_k(
    const unsigned short* __restrict__ A, int ldA,
    const unsigned short* __restrict__ Bt, int ldB,
    const unsigned short* __restrict__ bias,
    const unsigned short* resid,          // no restrict: may alias out
    unsigned short* out, int ldOut,
    const unsigned short* __restrict__ Bt2,
    const unsigned short* __restrict__ bias2,
    unsigned short* out2, int ldOut2,
    long M, int K)
{
    __shared__ unsigned short As[8192];
    __shared__ unsigned short Bs[8192];
    const int tid = threadIdx.x;
    const int l  = tid & 63;
    const int w  = tid >> 6;
    const int wm = w >> 1, wn = w & 1;
    const long row0 = (long)blockIdx.y * 128;
    const int  col0x = blockIdx.x * 128;

    const unsigned short* BtB  = Bt;
    const unsigned short* biasB = bias;
    unsigned short* outB = out;
    int ldO  = ldOut;
    int col0 = col0x;
    if (SPLIT && col0x >= 256) {
        BtB = Bt2; biasB = bias2; outB = out2; ldO = ldOut2; col0 = col0x - 256;
    }

    f32x4 acc[4][4];
#pragma unroll
    for (int i = 0; i < 4; ++i)
#pragma unroll
        for (int j = 0; j < 4; ++j) acc[i][j] = (f32x4){0.f, 0.f, 0.f, 0.f};

    // staging geometry: round i stages 16B chunk; tile row r = i*32 + (tid>>3)
    const int sr = tid >> 3;
    const int sg = tid & 7;

    for (int k0 = 0; k0 < K; k0 += 64) {
#pragma unroll
        for (int i = 0; i < 4; ++i) {
            const int r = i * 32 + sr;
            long arow = row0 + r; if (arow >= M) arow = M - 1;   // clamp tail
            const int ke = k0 + ((sg ^ (r & 7)) << 3);           // pre-swizzled src
            const unsigned short* ga = A   + arow * (long)ldA + ke;
            const unsigned short* gb = BtB + (long)(col0 + r) * ldB + ke;
            __builtin_amdgcn_global_load_lds(
                (const __attribute__((address_space(1))) void*)ga,
                (__attribute__((address_space(3))) void*)(As + i * 2048 + w * 512),
                16, 0, 0);
            __builtin_amdgcn_global_load_lds(
                (const __attribute__((address_space(1))) void*)gb,
                (__attribute__((address_space(3))) void*)(Bs + i * 2048 + w * 512),
                16, 0, 0);
        }
        __syncthreads();    // drains vmcnt, tiles ready
#pragma unroll
        for (int ks = 0; ks < 2; ++ks) {
            const int cc  = ks * 4 + (l >> 4);
            const int swz = ((cc ^ (l & 7)) << 4);
            bf16x8 af[4], bfr[4];
#pragma unroll
            for (int mi = 0; mi < 4; ++mi) {
                const int ar = wm * 64 + mi * 16 + (l & 15);
                af[mi] = *(const bf16x8*)((const char*)As + ar * 128 + swz);
            }
#pragma unroll
            for (int ni = 0; ni < 4; ++ni) {
                const int br = wn * 64 + ni * 16 + (l & 15);
                bfr[ni] = *(const bf16x8*)((const char*)Bs + br * 128 + swz);
            }
#pragma unroll
            for (int mi = 0; mi < 4; ++mi)
#pragma unroll
                for (int ni = 0; ni < 4; ++ni)
                    acc[mi][ni] = __builtin_amdgcn_mfma_f32_16x16x32_bf16(
                        af[mi], bfr[ni], acc[mi][ni], 0, 0, 0);
        }
        __syncthreads();    // compute done before next stage overwrites
    }

    // epilogue: C/D layout col=lane&15, row=(lane>>4)*4+r  [m89/m91]
#pragma unroll
    for (int ni = 0; ni < 4; ++ni) {
        const int col = col0 + wn * 64 + ni * 16 + (l & 15);
        const float bv = biasB ? bf2f(biasB[col]) : 0.f;
#pragma unroll
        for (int mi = 0; mi < 4; ++mi) {
            const long rbase = row0 + wm * 64 + mi * 16 + (l >> 4) * 4;
#pragma unroll
            for (int r = 0; r < 4; ++r) {
                const long rr = rbase + r;
                if (rr >= M) continue;
                float v = acc[mi][ni][r] + bv;
                if (RELU) v = fmaxf(v, 0.f);
                if (RESID) v += bf2f(resid[rr * (long)ldO + col]);
                outB[rr * (long)ldO + col] = f2bf(v);
            }
        }
    }
}

// ---------------------------------------------------------------------------
// Deformable sampling. One block per token.
// Prep (tid<128, u = h*16+lp): softmax fused via 16-lane __shfl_xor reduce,
// offsets/logits read directly from global (coalesced), tables written as
// [lp*8+h][4] BYTE offsets + weights -> gather reads them as int4/float4
// (2 LDS vector reads per j, 8 distinct addrs stride 16B, 8-way broadcast).
// Gather: tid = g*64 + h*8 + q; per j-step 4 unconditional uint2 loads
// (one wave-load = one full 512B token row, perfectly coalesced) + packed
// f32x2 fma (v_pk_fma_f32). Cross-wave reduce via LDS in [3][4][64] layout
// (b32 at 4B lane stride -> 2-way bank alias = free; the old [3][64][4]
// b128 writes at 16B stride were an 8-way conflict, 11.9M cycles/dispatch).
// ---------------------------------------------------------------------------
__global__ __launch_bounds__(256) void sample_k(
    const unsigned short* __restrict__ off, const unsigned short* __restrict__ aw,
    const unsigned short* __restrict__ val, unsigned short* __restrict__ attn)
{
    __shared__ __align__(16) int   cidx[128][4];   // byte offsets into val rows
    __shared__ __align__(16) float cw[128][4];
    __shared__ float red[3][4][64];
    const long tok = blockIdx.x;
    const int tid = threadIdx.x;
    const int b = (int)(tok / L_TOT);
    const int t = (int)(tok - (long)b * L_TOT);

    if (tid < 128) {
        const int u = tid;                       // u = h*16 + lp
        const int mu = (u & 15) * 8 + (u >> 4);  // [lp*8+h]
        // softmax over the 16 samples of this head (16-lane shfl groups)
        const float logit = bf2f(aw[tok * 128 + u]);
        float m = logit;
#pragma unroll
        for (int mk = 1; mk < 16; mk <<= 1) m = fmaxf(m, __shfl_xor(m, mk));
        const float e = expf(logit - m);
        float s = e;
#pragma unroll
        for (int mk = 1; mk < 16; mk <<= 1) s += __shfl_xor(s, mk);
        const float a = e / s;
        // token geometry
        int st0, W0;
        if (t < 10000)      { st0 = 0;     W0 = 100; }
        else if (t < 12500) { st0 = 10000; W0 = 50;  }
        else if (t < 13125) { st0 = 12500; W0 = 25;  }
        else                { st0 = 13125; W0 = 13;  }
        const int i0 = t - st0;
        const int yy = i0 / W0;
        const int xx = i0 - yy * W0;
        const float gx = (xx + 0.5f) / (float)W0;
        const float gy = (yy + 0.5f) / (float)W0;   // square levels
        // sample level
        const int lv = (u >> 2) & 3;
        const int Wv  = (lv == 0) ? 100 : (lv == 1) ? 50 : (lv == 2) ? 25 : 13;
        const int stl = (lv == 0) ? 0 : (lv == 1) ? 10000 : (lv == 2) ? 12500 : 13125;
        const unsigned int op = *(const unsigned int*)(off + tok * 256 + 2 * u);
        const float ox = bf2f((unsigned short)op);
        const float oy = bf2f((unsigned short)(op >> 16));
        const float px = (gx + ox / (float)Wv) * Wv - 0.5f;
        const float py = (gy + oy / (float)Wv) * Wv - 0.5f;
        const float fx = floorf(px), fy = floorf(py);
        const float wx1 = px - fx, wy1 = py - fy;
        const int x0 = (int)fx, y0 = (int)fy;
#pragma unroll
        for (int c = 0; c < 4; ++c) {
            const int xi = x0 + (c & 1);
            const int yi = y0 + (c >> 1);
            const float wgt = ((c & 1) ? wx1 : 1.f - wx1) * ((c >> 1) ? wy1 : 1.f - wy1);
            const bool ok = (xi >= 0) && (xi < Wv) && (yi >= 0) && (yi < Wv);
            cidx[mu][c] = ok ? ((stl + yi * Wv + xi) << 9) : 0;   // *512 bytes
            cw[mu][c]   = ok ? wgt * a : 0.f;
        }
    }
    __syncthreads();
    const int g = tid >> 6;                 // sample group (= wave)
    const int l = tid & 63;
    const int h = l >> 3;                   // head
    const int q = l & 7;                    // channel quad
    const char* vb = (const char*)val + ((long)b * L_TOT) * 512 + h * 64 + q * 8;
    f32x2 A01 = {0.f, 0.f}, A23 = {0.f, 0.f};
#pragma unroll
    for (int j = 0; j < 4; ++j) {
        const int mu = (j * 4 + g) * 8 + h;
        const int4   ci = *(const int4*)(&cidx[mu][0]);
        const float4 wv = *(const float4*)(&cw[mu][0]);
        const uint2 d0 = *(const uint2*)(vb + ci.x);
        const uint2 d1 = *(const uint2*)(vb + ci.y);
        const uint2 d2 = *(const uint2*)(vb + ci.z);
        const uint2 d3 = *(const uint2*)(vb + ci.w);
        A01 = fma2(bfpair(d0.x), wv.x, A01);  A23 = fma2(bfpair(d0.y), wv.x, A23);
        A01 = fma2(bfpair(d1.x), wv.y, A01);  A23 = fma2(bfpair(d1.y), wv.y, A23);
        A01 = fma2(bfpair(d2.x), wv.z, A01);  A23 = fma2(bfpair(d2.y), wv.z, A23);
        A01 = fma2(bfpair(d3.x), wv.w, A01);  A23 = fma2(bfpair(d3.y), wv.w, A23);
    }
    if (g) {
        red[g - 1][0][l] = A01.x; red[g - 1][1][l] = A01.y;
        red[g - 1][2][l] = A23.x; red[g - 1][3][l] = A23.y;
    }
    __syncthreads();
    if (g == 0) {
        float a0 = A01.x, a1 = A01.y, a2 = A23.x, a3 = A23.y;
#pragma unroll
        for (int p = 0; p < 3; ++p) {
            a0 += red[p][0][l]; a1 += red[p][1][l];
            a2 += red[p][2][l]; a3 += red[p][3][l];
        }
        ushort4 o;
        o.x = f2bf(a0); o.y = f2bf(a1); o.z = f2bf(a2); o.w = f2bf(a3);
        *(ushort4*)(attn + tok * 256 + h * 32 + q * 4) = o;
    }
}

// ---------------------------------------------------------------------------
// LayerNorm over D=256. Block = 4 waves = 4 tokens; lane = 4 channels.
// ---------------------------------------------------------------------------
__global__ __launch_bounds__(256) void ln_k(
    const unsigned short* __restrict__ y,
    const unsigned short* __restrict__ g, const unsigned short* __restrict__ bb,
    unsigned short* __restrict__ out, long nt)
{
    const int wv = threadIdx.x >> 6;
    const int lane = threadIdx.x & 63;
    const long tok = (long)blockIdx.x * 4 + wv;
    if (tok >= nt) return;
    const ushort4 v4 = *(const ushort4*)(y + tok * D + lane * 4);
    const float v0 = bf2f(v4.x), v1 = bf2f(v4.y), v2 = bf2f(v4.z), v3 = bf2f(v4.w);
    float s = v0 + v1 + v2 + v3;
#pragma unroll
    for (int m = 1; m < 64; m <<= 1) s += __shfl_xor(s, m);
    const float mean = s * (1.f / D);
    const float d0 = v0 - mean, d1 = v1 - mean, d2 = v2 - mean, d3 = v3 - mean;
    float q = d0 * d0 + d1 * d1 + d2 * d2 + d3 * d3;
#pragma unroll
    for (int m = 1; m < 64; m <<= 1) q += __shfl_xor(q, m);
    const float rstd = rsqrtf(q * (1.f / D) + 1e-5f);
    const int c0 = lane * 4;
    ushort4 o;
    o.x = f2bf(d0 * rstd * bf2f(g[c0 + 0]) + bf2f(bb[c0 + 0]));
    o.y = f2bf(d1 * rstd * bf2f(g[c0 + 1]) + bf2f(bb[c0 + 1]));
    o.z = f2bf(d2 * rstd * bf2f(g[c0 + 2]) + bf2f(bb[c0 + 2]));
    o.w = f2bf(d3 * rstd * bf2f(g[c0 + 3]) + bf2f(bb[c0 + 3]));
    *(ushort4*)(out + tok * D + lane * 4) = o;
}

// ---------------------------------------------------------------------------
// Finalize: OUTPUT IS FP32. d_out[0, osz-4) = final src (bf16 state -> f32);
// d_out[osz-4, osz) = level_start_index as f32.
// ---------------------------------------------------------------------------
__global__ __launch_bounds__(256) void finalize_k(
    const unsigned short* __restrict__ state, float* __restrict__ out, long osz)
{
    const long e = (long)blockIdx.x * 256 + threadIdx.x;
    const long n0 = osz - 4;
    if (e < n0) out[e] = bf2f(state[e]);
    if (e < 4) {
        const float st[4] = {0.f, 10000.f, 12500.f, 13125.f};
        out[n0 + e] = st[e];
    }
}

extern "C" void kernel_launch(void* const* d_in, const int* in_sizes, int n_in,
                              void* d_out, int out_size, void* d_ws, size_t ws_size,
                              hipStream_t stream)
{
    (void)n_in;
    const long osz = (long)out_size;
    const long nt = (osz - 4) / D;                      // total tokens
    const int nlayers = in_sizes[9] / (D * D);          // so_w: (NL, 256, 256)
    const int dff = in_sizes[19] / (nlayers * D);       // f1_w: (NL, 256, DFF)

    char* ws = (char*)d_ws;
    int* flag = (int*)ws;  ws += 256;
    unsigned short* wc = (unsigned short*)ws;           // canonical bf16 weights
    long off[25]; long acc_off = 0;
    for (int i = 8; i <= 24; ++i) { off[i] = acc_off; acc_off += in_sizes[i]; }
    ws += ((acc_off * 2 + 255) / 256) * 256;
    const size_t SZ_BF = (size_t)nt * D * 2;
    unsigned short* state     = (unsigned short*)ws;  ws += SZ_BF;  // running src (bf16)
    unsigned short* val_b     = (unsigned short*)ws;  ws += SZ_BF;  // value / h[:,0:256]
    unsigned short* offy_b    = (unsigned short*)ws;  ws += SZ_BF;  // offsets, y / h[:,256:512]
    unsigned short* posattn_b = (unsigned short*)ws;  ws += SZ_BF;  // q, then attn, then ffn-partial
    unsigned short* aw_b      = (unsigned short*)ws;  ws += (size_t)nt * 128 * 2;
    unsigned short* hbuf = val_b;   // [nt][dff/2] spans val_b..offy_b (contiguous)
    // base total ~131.5 MB @ B=4 (round-4-proven size)

    // optional +27 MB: layer-invariant pos buffer (guarded by ws_size)
    const size_t used_base = (size_t)((char*)aw_b - (char*)d_ws) + (size_t)nt * 128 * 2;
    const bool have_posc = (ws_size >= used_base + SZ_BF);
    unsigned short* posc = (unsigned short*)((char*)d_ws + used_base);

    probe_k<<<1, 256, 0, stream>>>((const unsigned short*)d_in[8], in_sizes[8], flag);

    // vectors/biases: plain convert
    const int vecIdx[11] = {8, 10, 12, 14, 16, 17, 18, 20, 22, 23, 24};
    for (int j = 0; j < 11; ++j) {
        const int i = vecIdx[j];
        convert_k<<<(in_sizes[i] + 255) / 256, 256, 0, stream>>>(
            d_in[i], wc + off[i], in_sizes[i], flag);
    }
    // matrices: convert + transpose to [N][K] for MFMA B-fragments
    const int matIdx[6] = {9, 11, 13, 15, 19, 21};
    const int matK[6]   = {D, D, D, D, D, dff};
    const int matN[6]   = {D, 128, D, D, dff, D};
    for (int j = 0; j < 6; ++j) {
        const int i = matIdx[j];
        convt_k<<<(in_sizes[i] + 255) / 256, 256, 0, stream>>>(
            d_in[i], wc + off[i], matK[j], matN[j], nlayers, flag);
    }

    flatten_k<<<(int)nt, 256, 0, stream>>>(
        d_in[0], d_in[2], d_in[4], d_in[6], flag, state);
    if (have_posc)
        posconst_k<<<(int)nt, 256, 0, stream>>>(
            d_in[1], d_in[3], d_in[5], d_in[7], wc + off[8], flag, posc);

    const int MB = (int)((nt + 127) / 128);
    const int LB = (int)((nt + 3) / 4);
    const long n8 = (long)nt * D / 8;
    const int AB = (int)((n8 + 255) / 256);
    const int dh = dff / 2;                     // 512: FFN split so h fits 2 buffers

    for (int i = 0; i < nlayers; ++i) {
        if (have_posc)
            addq_k<<<AB, 256, 0, stream>>>(state, posc, posattn_b, n8);
        else
            posflat_k<<<(int)nt, 256, 0, stream>>>(
                d_in[1], d_in[3], d_in[5], d_in[7], wc + off[8], flag, state, posattn_b);
        mgemm_k<false, false, false><<<dim3(2, MB), 256, 0, stream>>>( // value
            state, D, wc + off[13] + (long)i * D * D, D, wc + off[14] + i * D,
            nullptr, val_b, D, nullptr, nullptr, nullptr, 0, nt, D);
        // fused: sampling offsets (cols 0-255) + attn logits (cols 256-383)
        mgemm_k<false, false, true><<<dim3(3, MB), 256, 0, stream>>>(
            posattn_b, D, wc + off[9] + (long)i * D * 256, D, wc + off[10] + i * 256,
            nullptr, offy_b, D,
            wc + off[11] + (long)i * D * 128, wc + off[12] + i * 128, aw_b, 128,
            nt, D);
        sample_k<<<(int)nt, 256, 0, stream>>>(offy_b, aw_b, val_b, posattn_b);
        mgemm_k<false, true, false><<<dim3(2, MB), 256, 0, stream>>>(  // out-proj + resid
            posattn_b, D, wc + off[15] + (long)i * D * D, D, wc + off[16] + i * D,
            state, offy_b, D, nullptr, nullptr, nullptr, 0, nt, D);
        ln_k<<<LB, 256, 0, stream>>>(offy_b, wc + off[17] + i * D, wc + off[18] + i * D,
                                     state, nt);
        // FFN as 2 half-dff passes: partial = x + relu(x@W1a+b1a)@W2a + b2,
        // then partial += relu(x@W1b+b1b)@W2b.  h lives in val_b+offy_b.
        mgemm_k<true, false, false><<<dim3(dh / 128, MB), 256, 0, stream>>>(
            state, D, wc + off[19] + (long)i * D * dff, D, wc + off[20] + i * dff,
            nullptr, hbuf, dh, nullptr, nullptr, nullptr, 0, nt, D);
        mgemm_k<false, true, false><<<dim3(2, MB), 256, 0, stream>>>(
            hbuf, dh, wc + off[21] + (long)i * dff * D, dff, wc + off[22] + i * D,
            state, posattn_b, D, nullptr, nullptr, nullptr, 0, nt, dh);
        mgemm_k<true, false, false><<<dim3(dh / 128, MB), 256, 0, stream>>>(
            state, D, wc + off[19] + (long)i * D * dff + (long)dh * D, D,
            wc + off[20] + i * dff + dh, nullptr, hbuf, dh,
            nullptr, nullptr, nullptr, 0, nt, D);
        mgemm_k<false, true, false><<<dim3(2, MB), 256, 0, stream>>>(
            hbuf, dh, wc + off[21] + (long)i * dff * D + dh, dff, nullptr,
            posattn_b, posattn_b, D, nullptr, nullptr, nullptr, 0, nt, dh);
        ln_k<<<LB, 256, 0, stream>>>(posattn_b, wc + off[23] + i * D, wc + off[24] + i * D,
                                     state, nt);
    }

    finalize_k<<<(int)((osz - 4 + 255) / 256), 256, 0, stream>>>(
        state, (float*)d_out, osz);
}

// Round 6
// 2599.059 us; speedup vs baseline: 1.2998x; 1.1381x over previous
//
#include <hip/hip_runtime.h>

#define D 256
#define L_TOT 13294

typedef __attribute__((ext_vector_type(8))) __bf16 bf16x8;
typedef __attribute__((ext_vector_type(4))) float f32x4;
typedef __attribute__((ext_vector_type(2))) float f32x2;

__device__ __forceinline__ float bf2f(unsigned short u) {
    return __uint_as_float(((unsigned int)u) << 16);
}
__device__ __forceinline__ unsigned short f2bf(float f) {
    unsigned int u = __float_as_uint(f);
    u += 0x7FFFu + ((u >> 16) & 1u);   // round-to-nearest-even
    return (unsigned short)(u >> 16);
}
// two bf16 packed in a dword -> f32x2 {lo, hi}
__device__ __forceinline__ f32x2 bfpair(unsigned int d) {
    f32x2 r;
    r.x = __uint_as_float(d << 16);
    r.y = __uint_as_float(d & 0xFFFF0000u);
    return r;
}
__device__ __forceinline__ f32x2 fma2(f32x2 a, float w, f32x2 c) {
    return __builtin_elementwise_fma(a, (f32x2){w, w}, c);   // v_pk_fma_f32
}

// ---------------------------------------------------------------------------
// Dtype probe on level_embed: bf16 data -> ~100% sane exponents; fp32 read as
// halfwords -> ~60%. flag=1 means bf16 inputs.
// ---------------------------------------------------------------------------
__global__ void probe_k(const unsigned short* __restrict__ u, int n, int* __restrict__ flag)
{
    __shared__ int cnt;
    if (threadIdx.x == 0) cnt = 0;
    __syncthreads();
    int c = 0;
    for (int i = threadIdx.x; i < n; i += 256) {
        const int e = (u[i] >> 7) & 0xFF;
        if (e == 0 || (e >= 96 && e <= 150)) ++c;
    }
    atomicAdd(&cnt, c);
    __syncthreads();
    if (threadIdx.x == 0) *flag = (cnt * 10 > n * 9) ? 1 : 0;
}

__global__ __launch_bounds__(256) void convert_k(
    const void* __restrict__ src, unsigned short* __restrict__ dst, int n,
    const int* __restrict__ flag)
{
    const int i = blockIdx.x * 256 + threadIdx.x;
    if (i >= n) return;
    if (*flag) dst[i] = ((const unsigned short*)src)[i];
    else       dst[i] = f2bf(((const float*)src)[i]);
}

// Convert + transpose: src (L,K,N) -> dst (L,N,K) bf16.
__global__ __launch_bounds__(256) void convt_k(
    const void* __restrict__ src, unsigned short* __restrict__ dst,
    int K, int N, int L, const int* __restrict__ flag)
{
    const long e = (long)blockIdx.x * 256 + threadIdx.x;
    const long tot = (long)L * K * N;
    if (e >= tot) return;
    const int per = K * N;
    const int li = (int)(e / per);
    const int r  = (int)(e - (long)li * per);
    const int n  = r / K;
    const int k  = r - n * K;
    const long s = (long)li * per + (long)k * N + n;
    dst[e] = (*flag) ? ((const unsigned short*)src)[s]
                     : f2bf(((const float*)src)[s]);
}

// ---------------------------------------------------------------------------
// Flatten (B,D,H,W) src inputs -> state bf16 (tok,D).
// ---------------------------------------------------------------------------
__global__ __launch_bounds__(256) void flatten_k(
    const void* __restrict__ s0, const void* __restrict__ s1,
    const void* __restrict__ s2, const void* __restrict__ s3,
    const int* __restrict__ flag, unsigned short* __restrict__ state)
{
    const long e = (long)blockIdx.x * 256 + threadIdx.x;
    const int d = (int)(e & 255);
    const long tok = e >> 8;
    const int b = (int)(tok / L_TOT);
    const int t = (int)(tok - (long)b * L_TOT);
    const void *sp;
    int hw, idx;
    if (t < 10000)      { sp = s0; hw = 10000; idx = t;          }
    else if (t < 12500) { sp = s1; hw = 2500;  idx = t - 10000;  }
    else if (t < 13125) { sp = s2; hw = 625;   idx = t - 12500;  }
    else                { sp = s3; hw = 169;   idx = t - 13125;  }
    const long a = ((long)b * D + d) * hw + idx;
    state[e] = (*flag) ? ((const unsigned short*)sp)[a]
                       : f2bf(((const float*)sp)[a]);
}

// Layer-invariant pos precompute: posc = pos_input + level_embed (bf16).
__global__ __launch_bounds__(256) void posconst_k(
    const void* __restrict__ p0, const void* __restrict__ p1,
    const void* __restrict__ p2, const void* __restrict__ p3,
    const unsigned short* __restrict__ lev, const int* __restrict__ flag,
    unsigned short* __restrict__ posc)
{
    const long e = (long)blockIdx.x * 256 + threadIdx.x;
    const int d = (int)(e & 255);
    const long tok = e >> 8;
    const int b = (int)(tok / L_TOT);
    const int t = (int)(tok - (long)b * L_TOT);
    const void *pp;
    int hw, idx, l;
    if (t < 10000)      { pp = p0; hw = 10000; idx = t;          l = 0; }
    else if (t < 12500) { pp = p1; hw = 2500;  idx = t - 10000;  l = 1; }
    else if (t < 13125) { pp = p2; hw = 625;   idx = t - 12500;  l = 2; }
    else                { pp = p3; hw = 169;   idx = t - 13125;  l = 3; }
    const long a = ((long)b * D + d) * hw + idx;
    const float pv = (*flag) ? bf2f(((const unsigned short*)pp)[a])
                             : ((const float*)pp)[a];
    posc[e] = f2bf(pv + bf2f(lev[l * D + d]));
}

// q = x + posc, fully coalesced uint4 (8 bf16/thread). (layer-0 only)
__global__ __launch_bounds__(256) void addq_k(
    const unsigned short* __restrict__ x, const unsigned short* __restrict__ p,
    unsigned short* __restrict__ q, long n8)
{
    const long e = (long)blockIdx.x * 256 + threadIdx.x;
    if (e >= n8) return;
    const uint4 xv = ((const uint4*)x)[e];
    const uint4 pv = ((const uint4*)p)[e];
    uint4 o;
#define ADDPK(a, b) ({ const f32x2 fa = bfpair(a), fb = bfpair(b); \
        (unsigned int)f2bf(fb.x + fa.x) | ((unsigned int)f2bf(fb.y + fa.y) << 16); })
    o.x = ADDPK(xv.x, pv.x); o.y = ADDPK(xv.y, pv.y);
    o.z = ADDPK(xv.z, pv.z); o.w = ADDPK(xv.w, pv.w);
#undef ADDPK
    ((uint4*)q)[e] = o;
}

// Fallback (tight workspace): per-layer q = x + pos_input + level_embed.
__global__ __launch_bounds__(256) void posflat_k(
    const void* __restrict__ p0, const void* __restrict__ p1,
    const void* __restrict__ p2, const void* __restrict__ p3,
    const unsigned short* __restrict__ lev, const int* __restrict__ flag,
    const unsigned short* __restrict__ x, unsigned short* __restrict__ q)
{
    const long e = (long)blockIdx.x * 256 + threadIdx.x;
    const int d = (int)(e & 255);
    const long tok = e >> 8;
    const int b = (int)(tok / L_TOT);
    const int t = (int)(tok - (long)b * L_TOT);
    const void *pp;
    int hw, idx, l;
    if (t < 10000)      { pp = p0; hw = 10000; idx = t;          l = 0; }
    else if (t < 12500) { pp = p1; hw = 2500;  idx = t - 10000;  l = 1; }
    else if (t < 13125) { pp = p2; hw = 625;   idx = t - 12500;  l = 2; }
    else                { pp = p3; hw = 169;   idx = t - 13125;  l = 3; }
    const long a = ((long)b * D + d) * hw + idx;
    const float pv = (*flag) ? bf2f(((const unsigned short*)pp)[a])
                             : ((const float*)pp)[a];
    q[e] = f2bf(pv + bf2f(lev[l * D + d]) + bf2f(x[e]));
}

// ---------------------------------------------------------------------------
// MFMA GEMM core, single-buffered m97 structure (R3 lesson: dbuf 64KB LDS
// dropped occupancy 3->2 and regressed). Tile 128x128, BK=64, 4 waves (2x2).
// OPERANDS SWAPPED: acc = mfma(bfr, af, acc) -> lane holds row (l&15) and 4
// CONSECUTIVE cols (l>>4)*4+r of C (C/D map col=lane&15,row=(lane>>4)*4+reg
// [m89] applied to the swapped free dims). bias/resid/store are all ushort4
// (16x8B stores/thread vs the 64x2B scatter that dominated the old epilogue).
// LDS XOR-swizzle in 16B groups (G4); global source pre-swizzled (rule #21).
// ---------------------------------------------------------------------------
template<bool RELU, bool RESID>
__device__ __forceinline__ void gemm_core(
    const unsigned short* __restrict__ A, int ldA,
    const unsigned short* __restrict__ Bt, int ldB,
    const unsigned short* __restrict__ bias,
    const unsigned short* resid,          // may alias out
    unsigned short* out, int ldO,
    long M, int K, int col0, long row0,
    unsigned short* As, unsigned short* Bs)
{
    const int tid = threadIdx.x;
    const int l  = tid & 63;
    const int w  = tid >> 6;
    const int wm = w >> 1, wn = w & 1;

    f32x4 acc[4][4];
#pragma unroll
    for (int i = 0; i < 4; ++i)
#pragma unroll
        for (int j = 0; j < 4; ++j) acc[i][j] = (f32x4){0.f, 0.f, 0.f, 0.f};

    const int sr = tid >> 3;
    const int sg = tid & 7;

    for (int k0 = 0; k0 < K; k0 += 64) {
#pragma unroll
        for (int i = 0; i < 4; ++i) {
            const int r = i * 32 + sr;
            long arow = row0 + r; if (arow >= M) arow = M - 1;   // clamp tail
            const int ke = k0 + ((sg ^ (r & 7)) << 3);           // pre-swizzled src
            const unsigned short* ga = A  + arow * (long)ldA + ke;
            const unsigned short* gb = Bt + (long)(col0 + r) * ldB + ke;
            __builtin_amdgcn_global_load_lds(
                (const __attribute__((address_space(1))) void*)ga,
                (__attribute__((address_space(3))) void*)(As + i * 2048 + w * 512),
                16, 0, 0);
            __builtin_amdgcn_global_load_lds(
                (const __attribute__((address_space(1))) void*)gb,
                (__attribute__((address_space(3))) void*)(Bs + i * 2048 + w * 512),
                16, 0, 0);
        }
        __syncthreads();    // drains vmcnt, tiles ready
#pragma unroll
        for (int ks = 0; ks < 2; ++ks) {
            const int cc  = ks * 4 + (l >> 4);
            const int swz = ((cc ^ (l & 7)) << 4);
            bf16x8 af[4], bfr[4];
#pragma unroll
            for (int mi = 0; mi < 4; ++mi) {
                const int ar = wm * 64 + mi * 16 + (l & 15);
                af[mi] = *(const bf16x8*)((const char*)As + ar * 128 + swz);
            }
#pragma unroll
            for (int ni = 0; ni < 4; ++ni) {
                const int br = wn * 64 + ni * 16 + (l & 15);
                bfr[ni] = *(const bf16x8*)((const char*)Bs + br * 128 + swz);
            }
#pragma unroll
            for (int mi = 0; mi < 4; ++mi)
#pragma unroll
                for (int ni = 0; ni < 4; ++ni)
                    acc[mi][ni] = __builtin_amdgcn_mfma_f32_16x16x32_bf16(
                        bfr[ni], af[mi], acc[mi][ni], 0, 0, 0);   // SWAPPED -> C^T frag
        }
        __syncthreads();    // compute done before next stage overwrites
    }

    // epilogue: lane holds row (l&15), 4 consecutive cols (l>>4)*4+r
#pragma unroll
    for (int mi = 0; mi < 4; ++mi) {
        const long rr = row0 + wm * 64 + mi * 16 + (l & 15);
        if (rr >= M) continue;
#pragma unroll
        for (int ni = 0; ni < 4; ++ni) {
            const int col = col0 + wn * 64 + ni * 16 + (l >> 4) * 4;
            f32x4 v = acc[mi][ni];
            if (bias) {
                const ushort4 b4 = *(const ushort4*)(bias + col);
                v[0] += bf2f(b4.x); v[1] += bf2f(b4.y);
                v[2] += bf2f(b4.z); v[3] += bf2f(b4.w);
            }
            if (RELU) {
                v[0] = fmaxf(v[0], 0.f); v[1] = fmaxf(v[1], 0.f);
                v[2] = fmaxf(v[2], 0.f); v[3] = fmaxf(v[3], 0.f);
            }
            if (RESID) {
                const ushort4 r4 = *(const ushort4*)(resid + rr * (long)ldO + col);
                v[0] += bf2f(r4.x); v[1] += bf2f(r4.y);
                v[2] += bf2f(r4.z); v[3] += bf2f(r4.w);
            }
            ushort4 o;
            o.x = f2bf(v[0]); o.y = f2bf(v[1]); o.z = f2bf(v[2]); o.w = f2bf(v[3]);
            *(ushort4*)(out + rr * (long)ldO + col) = o;
        }
    }
}

template<bool RELU, bool RESID>
__global__ __launch_bounds__(256, 3) void mgemm_k(
    const unsigned short* __restrict__ A, int ldA,
    const unsigned short* __restrict__ Bt, int ldB,
    const unsigned short* __restrict__ bias,
    const unsigned short* resid,
    unsigned short* out, int ldOut,
    long M, int K)
{
    __shared__ unsigned short As[8192];
    __shared__ unsigned short Bs[8192];
    gemm_core<RELU, RESID>(A, ldA, Bt, ldB, bias, resid, out, ldOut,
                           M, K, blockIdx.x * 128, (long)blockIdx.y * 128, As, Bs);
}

// Merged value + sampling-offsets + attn-logits (one dispatch; segment select
// is block-uniform). grid = dim3(5, MB): cols 0-1 value, 2-3 offsets, 4 logits.
__global__ __launch_bounds__(256, 3) void mgemm3_k(
    const unsigned short* __restrict__ state, const unsigned short* __restrict__ q,
    const unsigned short* __restrict__ Wv,  const unsigned short* __restrict__ bv,
    const unsigned short* __restrict__ Wso, const unsigned short* __restrict__ bso,
    const unsigned short* __restrict__ Waw, const unsigned short* __restrict__ baw,
    unsigned short* valo, unsigned short* offo, unsigned short* awo, long M)
{
    __shared__ unsigned short As[8192];
    __shared__ unsigned short Bs[8192];
    const int cx = blockIdx.x * 128;
    const long row0 = (long)blockIdx.y * 128;
    if (cx < 256)
        gemm_core<false, false>(state, D, Wv, D, bv, nullptr, valo, D,
                                M, D, cx, row0, As, Bs);
    else if (cx < 512)
        gemm_core<false, false>(q, D, Wso, D, bso, nullptr, offo, D,
                                M, D, cx - 256, row0, As, Bs);
    else
        gemm_core<false, false>(q, D, Waw, D, baw, nullptr, awo, 128,
                                M, D, 0, row0, As, Bs);
}

// ---------------------------------------------------------------------------
// Deformable sampling. One block per token.
// Prep (tid<128, u=h*16+lp): tables at [mu=lp*8+h][c ^ (lp&3)].
//   Bank = (4h + (c^(lp&3)))&31 -> 4-way write conflict (was 16-way: bank
//   (4h+c) was lp-independent -> the 11.9M conflict cycles). The XOR permutes
//   (idx,weight) PAIRS identically and the gather sums over corners, so no
//   unpermute is needed (in-wave lp&3 = g is uniform).
// Gather: tid = g*64+h*8+q; int4/float4 table reads (conflict-free broadcast),
// 4 unconditional uint2 loads/j + packed f32x2 fma. Cross-wave reduce via
// [3][4][64] LDS (4B lane stride, 2-way = free).
// ---------------------------------------------------------------------------
__global__ __launch_bounds__(256) void sample_k(
    const unsigned short* __restrict__ off, const unsigned short* __restrict__ aw,
    const unsigned short* __restrict__ val, unsigned short* __restrict__ attn)
{
    __shared__ __align__(16) int   cidx[128][4];   // byte offsets into val rows
    __shared__ __align__(16) float cw[128][4];
    __shared__ float red[3][4][64];
    const long tok = blockIdx.x;
    const int tid = threadIdx.x;
    const int b = (int)(tok / L_TOT);
    const int t = (int)(tok - (long)b * L_TOT);

    if (tid < 128) {
        const int u = tid;                       // u = h*16 + lp
        const int lp = u & 15;
        const int mu = lp * 8 + (u >> 4);        // [lp*8+h]
        const int cswz = lp & 3;                 // pair-preserving bank swizzle
        // softmax over the 16 samples of this head (16-lane shfl groups)
        const float logit = bf2f(aw[tok * 128 + u]);
        float m = logit;
#pragma unroll
        for (int mk = 1; mk < 16; mk <<= 1) m = fmaxf(m, __shfl_xor(m, mk));
        const float e = expf(logit - m);
        float s = e;
#pragma unroll
        for (int mk = 1; mk < 16; mk <<= 1) s += __shfl_xor(s, mk);
        const float a = e / s;
        // token geometry
        int st0, W0;
        if (t < 10000)      { st0 = 0;     W0 = 100; }
        else if (t < 12500) { st0 = 10000; W0 = 50;  }
        else if (t < 13125) { st0 = 12500; W0 = 25;  }
        else                { st0 = 13125; W0 = 13;  }
        const int i0 = t - st0;
        const int yy = i0 / W0;
        const int xx = i0 - yy * W0;
        const float gx = (xx + 0.5f) / (float)W0;
        const float gy = (yy + 0.5f) / (float)W0;   // square levels
        // sample level
        const int lv = (u >> 2) & 3;
        const int Wv  = (lv == 0) ? 100 : (lv == 1) ? 50 : (lv == 2) ? 25 : 13;
        const int stl = (lv == 0) ? 0 : (lv == 1) ? 10000 : (lv == 2) ? 12500 : 13125;
        const unsigned int op = *(const unsigned int*)(off + tok * 256 + 2 * u);
        const float ox = bf2f((unsigned short)op);
        const float oy = bf2f((unsigned short)(op >> 16));
        const float px = (gx + ox / (float)Wv) * Wv - 0.5f;
        const float py = (gy + oy / (float)Wv) * Wv - 0.5f;
        const float fx = floorf(px), fy = floorf(py);
        const float wx1 = px - fx, wy1 = py - fy;
        const int x0 = (int)fx, y0 = (int)fy;
#pragma unroll
        for (int c = 0; c < 4; ++c) {
            const int xi = x0 + (c & 1);
            const int yi = y0 + (c >> 1);
            const float wgt = ((c & 1) ? wx1 : 1.f - wx1) * ((c >> 1) ? wy1 : 1.f - wy1);
            const bool ok = (xi >= 0) && (xi < Wv) && (yi >= 0) && (yi < Wv);
            cidx[mu][c ^ cswz] = ok ? ((stl + yi * Wv + xi) << 9) : 0;   // *512 B
            cw[mu][c ^ cswz]   = ok ? wgt * a : 0.f;
        }
    }
    __syncthreads();
    const int g = tid >> 6;                 // sample group (= wave)
    const int l = tid & 63;
    const int h = l >> 3;                   // head
    const int q = l & 7;                    // channel quad
    const char* vb = (const char*)val + ((long)b * L_TOT) * 512 + h * 64 + q * 8;
    f32x2 A01 = {0.f, 0.f}, A23 = {0.f, 0.f};
#pragma unroll
    for (int j = 0; j < 4; ++j) {
        const int mu = (j * 4 + g) * 8 + h;
        const int4   ci = *(const int4*)(&cidx[mu][0]);
        const float4 wv = *(const float4*)(&cw[mu][0]);
        const uint2 d0 = *(const uint2*)(vb + ci.x);
        const uint2 d1 = *(const uint2*)(vb + ci.y);
        const uint2 d2 = *(const uint2*)(vb + ci.z);
        const uint2 d3 = *(const uint2*)(vb + ci.w);
        A01 = fma2(bfpair(d0.x), wv.x, A01);  A23 = fma2(bfpair(d0.y), wv.x, A23);
        A01 = fma2(bfpair(d1.x), wv.y, A01);  A23 = fma2(bfpair(d1.y), wv.y, A23);
        A01 = fma2(bfpair(d2.x), wv.z, A01);  A23 = fma2(bfpair(d2.y), wv.z, A23);
        A01 = fma2(bfpair(d3.x), wv.w, A01);  A23 = fma2(bfpair(d3.y), wv.w, A23);
    }
    if (g) {
        red[g - 1][0][l] = A01.x; red[g - 1][1][l] = A01.y;
        red[g - 1][2][l] = A23.x; red[g - 1][3][l] = A23.y;
    }
    __syncthreads();
    if (g == 0) {
        float a0 = A01.x, a1 = A01.y, a2 = A23.x, a3 = A23.y;
#pragma unroll
        for (int p = 0; p < 3; ++p) {
            a0 += red[p][0][l]; a1 += red[p][1][l];
            a2 += red[p][2][l]; a3 += red[p][3][l];
        }
        ushort4 o;
        o.x = f2bf(a0); o.y = f2bf(a1); o.z = f2bf(a2); o.w = f2bf(a3);
        *(ushort4*)(attn + tok * 256 + h * 32 + q * 4) = o;
    }
}

// ---------------------------------------------------------------------------
// LayerNorm over D=256. Block = 4 waves = 4 tokens; lane = 4 channels.
// QOUT: also emit q = bf16(out) + posc (bit-exact with the old addq pass).
// ---------------------------------------------------------------------------
template<bool QOUT>
__global__ __launch_bounds__(256) void ln_k(
    const unsigned short* __restrict__ y,
    const unsigned short* __restrict__ g, const unsigned short* __restrict__ bb,
    unsigned short* __restrict__ out,
    const unsigned short* __restrict__ posc, unsigned short* __restrict__ qout,
    long nt)
{
    const int wv = threadIdx.x >> 6;
    const int lane = threadIdx.x & 63;
    const long tok = (long)blockIdx.x * 4 + wv;
    if (tok >= nt) return;
    const ushort4 v4 = *(const ushort4*)(y + tok * D + lane * 4);
    const float v0 = bf2f(v4.x), v1 = bf2f(v4.y), v2 = bf2f(v4.z), v3 = bf2f(v4.w);
    float s = v0 + v1 + v2 + v3;
#pragma unroll
    for (int m = 1; m < 64; m <<= 1) s += __shfl_xor(s, m);
    const float mean = s * (1.f / D);
    const float d0 = v0 - mean, d1 = v1 - mean, d2 = v2 - mean, d3 = v3 - mean;
    float q = d0 * d0 + d1 * d1 + d2 * d2 + d3 * d3;
#pragma unroll
    for (int m = 1; m < 64; m <<= 1) q += __shfl_xor(q, m);
    const float rstd = rsqrtf(q * (1.f / D) + 1e-5f);
    const int c0 = lane * 4;
    ushort4 o;
    o.x = f2bf(d0 * rstd * bf2f(g[c0 + 0]) + bf2f(bb[c0 + 0]));
    o.y = f2bf(d1 * rstd * bf2f(g[c0 + 1]) + bf2f(bb[c0 + 1]));
    o.z = f2bf(d2 * rstd * bf2f(g[c0 + 2]) + bf2f(bb[c0 + 2]));
    o.w = f2bf(d3 * rstd * bf2f(g[c0 + 3]) + bf2f(bb[c0 + 3]));
    *(ushort4*)(out + tok * D + c0) = o;
    if (QOUT) {
        const ushort4 p4 = *(const ushort4*)(posc + tok * D + c0);
        ushort4 qo;
        qo.x = f2bf(bf2f(o.x) + bf2f(p4.x));
        qo.y = f2bf(bf2f(o.y) + bf2f(p4.y));
        qo.z = f2bf(bf2f(o.z) + bf2f(p4.z));
        qo.w = f2bf(bf2f(o.w) + bf2f(p4.w));
        *(ushort4*)(qout + tok * D + c0) = qo;
    }
}

// ---------------------------------------------------------------------------
// Finalize: OUTPUT IS FP32.
// ---------------------------------------------------------------------------
__global__ __launch_bounds__(256) void finalize_k(
    const unsigned short* __restrict__ state, float* __restrict__ out, long osz)
{
    const long e = (long)blockIdx.x * 256 + threadIdx.x;
    const long n0 = osz - 4;
    if (e < n0) out[e] = bf2f(state[e]);
    if (e < 4) {
        const float st[4] = {0.f, 10000.f, 12500.f, 13125.f};
        out[n0 + e] = st[e];
    }
}

extern "C" void kernel_launch(void* const* d_in, const int* in_sizes, int n_in,
                              void* d_out, int out_size, void* d_ws, size_t ws_size,
                              hipStream_t stream)
{
    (void)n_in;
    const long osz = (long)out_size;
    const long nt = (osz - 4) / D;                      // total tokens
    const int nlayers = in_sizes[9] / (D * D);          // so_w: (NL, 256, 256)
    const int dff = in_sizes[19] / (nlayers * D);       // f1_w: (NL, 256, DFF)

    char* ws = (char*)d_ws;
    int* flag = (int*)ws;  ws += 256;
    unsigned short* wc = (unsigned short*)ws;           // canonical bf16 weights
    long off[25]; long acc_off = 0;
    for (int i = 8; i <= 24; ++i) { off[i] = acc_off; acc_off += in_sizes[i]; }
    ws += ((acc_off * 2 + 255) / 256) * 256;
    const size_t SZ_BF = (size_t)nt * D * 2;
    unsigned short* state     = (unsigned short*)ws;  ws += SZ_BF;  // running src
    unsigned short* val_b     = (unsigned short*)ws;  ws += SZ_BF;  // value / h lo
    unsigned short* offy_b    = (unsigned short*)ws;  ws += SZ_BF;  // offsets,y / h hi
    unsigned short* posattn_b = (unsigned short*)ws;  ws += SZ_BF;  // q, attn, ffn part
    unsigned short* aw_b      = (unsigned short*)ws;  ws += (size_t)nt * 128 * 2;
    unsigned short* hbuf = val_b;   // [nt][dff/2] spans val_b..offy_b (contiguous)

    // optional +27 MB: layer-invariant pos buffer (guarded by ws_size)
    const size_t used_base = (size_t)((char*)aw_b - (char*)d_ws) + (size_t)nt * 128 * 2;
    const bool have_posc = (ws_size >= used_base + SZ_BF);
    unsigned short* posc = (unsigned short*)((char*)d_ws + used_base);

    probe_k<<<1, 256, 0, stream>>>((const unsigned short*)d_in[8], in_sizes[8], flag);

    // vectors/biases: plain convert
    const int vecIdx[11] = {8, 10, 12, 14, 16, 17, 18, 20, 22, 23, 24};
    for (int j = 0; j < 11; ++j) {
        const int i = vecIdx[j];
        convert_k<<<(in_sizes[i] + 255) / 256, 256, 0, stream>>>(
            d_in[i], wc + off[i], in_sizes[i], flag);
    }
    // matrices: convert + transpose to [N][K] for MFMA B-fragments
    const int matIdx[6] = {9, 11, 13, 15, 19, 21};
    const int matK[6]   = {D, D, D, D, D, dff};
    const int matN[6]   = {D, 128, D, D, dff, D};
    for (int j = 0; j < 6; ++j) {
        const int i = matIdx[j];
        convt_k<<<(in_sizes[i] + 255) / 256, 256, 0, stream>>>(
            d_in[i], wc + off[i], matK[j], matN[j], nlayers, flag);
    }

    flatten_k<<<(int)nt, 256, 0, stream>>>(
        d_in[0], d_in[2], d_in[4], d_in[6], flag, state);
    if (have_posc)
        posconst_k<<<(int)nt, 256, 0, stream>>>(
            d_in[1], d_in[3], d_in[5], d_in[7], wc + off[8], flag, posc);

    const int MB = (int)((nt + 127) / 128);
    const int LB = (int)((nt + 3) / 4);
    const long n8 = (long)nt * D / 8;
    const int AB = (int)((n8 + 255) / 256);
    const int dh = dff / 2;                     // 512: FFN split, h fits 2 buffers

    if (have_posc)                              // layer-0 q
        addq_k<<<AB, 256, 0, stream>>>(state, posc, posattn_b, n8);

    for (int i = 0; i < nlayers; ++i) {
        if (!have_posc)
            posflat_k<<<(int)nt, 256, 0, stream>>>(
                d_in[1], d_in[3], d_in[5], d_in[7], wc + off[8], flag, state, posattn_b);
        // merged: value (cols 0-255) | offsets (256-511) | logits (512-639)
        mgemm3_k<<<dim3(5, MB), 256, 0, stream>>>(
            state, posattn_b,
            wc + off[13] + (long)i * D * D,   wc + off[14] + i * D,
            wc + off[9]  + (long)i * D * 256, wc + off[10] + i * 256,
            wc + off[11] + (long)i * D * 128, wc + off[12] + i * 128,
            val_b, offy_b, aw_b, nt);
        sample_k<<<(int)nt, 256, 0, stream>>>(offy_b, aw_b, val_b, posattn_b);
        mgemm_k<false, true><<<dim3(2, MB), 256, 0, stream>>>(  // out-proj + resid
            posattn_b, D, wc + off[15] + (long)i * D * D, D, wc + off[16] + i * D,
            state, offy_b, D, nt, D);
        ln_k<false><<<LB, 256, 0, stream>>>(offy_b, wc + off[17] + i * D,
            wc + off[18] + i * D, state, nullptr, nullptr, nt);
        // FFN as 2 half-dff passes
        mgemm_k<true, false><<<dim3(dh / 128, MB), 256, 0, stream>>>(
            state, D, wc + off[19] + (long)i * D * dff, D, wc + off[20] + i * dff,
            nullptr, hbuf, dh, nt, D);
        mgemm_k<false, true><<<dim3(2, MB), 256, 0, stream>>>(
            hbuf, dh, wc + off[21] + (long)i * dff * D, dff, wc + off[22] + i * D,
            state, posattn_b, D, nt, dh);
        mgemm_k<true, false><<<dim3(dh / 128, MB), 256, 0, stream>>>(
            state, D, wc + off[19] + (long)i * D * dff + (long)dh * D, D,
            wc + off[20] + i * dff + dh, nullptr, hbuf, dh, nt, D);
        mgemm_k<false, true><<<dim3(2, MB), 256, 0, stream>>>(
            hbuf, dh, wc + off[21] + (long)i * dff * D + dh, dff, nullptr,
            posattn_b, posattn_b, D, nt, dh);
        // ln2; for all but last layer also emit next-layer q = bf16(out)+posc
        if (have_posc && i + 1 < nlayers)
            ln_k<true><<<LB, 256, 0, stream>>>(posattn_b, wc + off[23] + i * D,
                wc + off[24] + i * D, state, posc, posattn_b, nt);
        else
            ln_k<false><<<LB, 256, 0, stream>>>(posattn_b, wc + off[23] + i * D,
                wc + off[24] + i * D, state, nullptr, nullptr, nt);
    }

    finalize_k<<<(int)((osz - 4 + 255) / 256), 256, 0, stream>>>(
        state, (float*)d_out, osz);
}